// Round 12
// baseline (375.457 us; speedup 1.0000x reference)
//
#include <hip/hip_runtime.h>
#include <hip/hip_fp16.h>

#define NBSHIFT 8
#define BSZ     256     // nodes per bucket
#define CAP     5120    // fixed bucket capacity (mean 4092, sigma 64 -> +16 sigma)
#define EBLK    8192    // edges per binning block

typedef _Float16 f16x8 __attribute__((ext_vector_type(8)));
typedef float    f32x4 __attribute__((ext_vector_type(4)));

#define GEMM_LDS_BYTES (128 * 136 * 2 + 512)

// ---------------- self-contained MFMA GEMM body: 512 threads, 128 rows ----------------
// Round-11 lesson: ROWG=4 with 256 thr starved the grid (2.3 blocks/CU, occ 16%).
// This variant amortizes staging 2x while KEEPING round-6's total wave count:
// 8 waves/block x 782 blocks = 6256 waves (round 6: 4 x 1563 = 6252). Staging
// (svd + sWh) serves 128 rows instead of 64.
template <bool XHALF>
__device__ __forceinline__ void gemm_body(
        const void* __restrict__ Xv, const float* __restrict__ Ws,
        const float* __restrict__ Wd, const float* __restrict__ attd,
        const float* __restrict__ att,
        __half* __restrict__ Y, float* __restrict__ a_s, float* __restrict__ a_d,
        int N, int blk, char* smem) {
    _Float16 (*sWh)[136] = (_Float16(*)[136])smem;
    float* svd = (float*)(smem + 128 * 136 * 2);
    int t = threadIdx.x;

    // vd[k] = dot(Wd row k, attd)
    if (t < 128) {
        const float4* wr = (const float4*)&Wd[t * 128];
        const float4* ar = (const float4*)attd;
        float s = 0.f;
#pragma unroll 8
        for (int j = 0; j < 32; j++) {
            float4 w = wr[j], a = ar[j];
            s += w.x * a.x + w.y * a.y + w.z * a.z + w.w * a.w;
        }
        svd[t] = s;
    }
    // sWh[n][k] = (fp16) Ws[k*128+n]; 512 threads -> 8 iters
#pragma unroll
    for (int i = 0; i < 8; i++) {
        int gid = t + i * 512;       // 0..4095
        int n = gid & 127, kq = gid >> 7;
        _Float16 p[4];
        p[0] = (_Float16)Ws[(kq * 4 + 0) * 128 + n];
        p[1] = (_Float16)Ws[(kq * 4 + 1) * 128 + n];
        p[2] = (_Float16)Ws[(kq * 4 + 2) * 128 + n];
        p[3] = (_Float16)Ws[(kq * 4 + 3) * 128 + n];
        *(uint2*)&sWh[n][kq * 4] = *(uint2*)p;
    }
    __syncthreads();

    int l = t & 63, wv = t >> 6;          // wv: 0..7
    int quad = l >> 4, lm = l & 15;
    int rbase = blk * 128 + wv * 16;
    int arow = rbase + lm;
    bool rok = arow < N;

    f32x4 acc[8];
#pragma unroll
    for (int c = 0; c < 8; c++) acc[c] = (f32x4){0.f, 0.f, 0.f, 0.f};
    float adp = 0.f;

#pragma unroll
    for (int kc = 0; kc < 4; kc++) {
        int k0 = kc * 32 + quad * 8;
        float xf[8];
        f16x8 af;
        if constexpr (XHALF) {
            const __half* xrow = (const __half*)Xv + (size_t)arow * 128;
            if (rok) {
                af = *(const f16x8*)&xrow[k0];
            } else {
#pragma unroll
                for (int j = 0; j < 8; j++) af[j] = (_Float16)0.f;
            }
#pragma unroll
            for (int j = 0; j < 8; j++) xf[j] = (float)af[j];
        } else {
            const float* xrow = (const float*)Xv + (size_t)arow * 128;
            if (rok) {
                *(float4*)&xf[0] = *(const float4*)&xrow[k0];
                *(float4*)&xf[4] = *(const float4*)&xrow[k0 + 4];
            } else {
#pragma unroll
                for (int j = 0; j < 8; j++) xf[j] = 0.f;
            }
#pragma unroll
            for (int j = 0; j < 8; j++) af[j] = (_Float16)xf[j];
        }
        float4 v0 = *(const float4*)&svd[k0];       // broadcast within quad
        float4 v1 = *(const float4*)&svd[k0 + 4];
        adp += xf[0] * v0.x + xf[1] * v0.y + xf[2] * v0.z + xf[3] * v0.w
             + xf[4] * v1.x + xf[5] * v1.y + xf[6] * v1.z + xf[7] * v1.w;
#pragma unroll
        for (int c = 0; c < 8; c++) {
            f16x8 bf = *(const f16x8*)&sWh[c * 16 + lm][k0];   // col n = c*16+lm
            acc[c] = __builtin_amdgcn_mfma_f32_16x16x32_f16(af, bf, acc[c], 0, 0, 0);
        }
    }

    adp += __shfl_xor(adp, 16);
    adp += __shfl_xor(adp, 32);
    if (quad == 0 && rok) a_d[arow] = adp;

    float attc[8];
#pragma unroll
    for (int c = 0; c < 8; c++) attc[c] = att[c * 16 + lm];
#pragma unroll
    for (int r = 0; r < 4; r++) {
        int grow = rbase + quad * 4 + r;
        bool gok = grow < N;
        float p = 0.f;
#pragma unroll
        for (int c = 0; c < 8; c++) {
            if (gok) Y[(size_t)grow * 128 + c * 16 + lm] = __float2half(acc[c][r]);
            p += acc[c][r] * attc[c];
        }
        p += __shfl_xor(p, 1); p += __shfl_xor(p, 2); p += __shfl_xor(p, 4); p += __shfl_xor(p, 8);
        if (lm == 0 && gok) a_s[grow] = p;
    }
}

// ---------------- FUSED: layer-1 GEMM (blocks < gb) + bucket pair placement ----------------
__global__ __launch_bounds__(512, 8) void k_fuse1(
        const float* __restrict__ X, const float* __restrict__ W1s,
        const float* __restrict__ W1d, const float* __restrict__ a1d,
        const float* __restrict__ a1s,
        __half* __restrict__ Y, float* __restrict__ a_s, float* __restrict__ a_d, int N, int gb,
        const int* __restrict__ src, const int* __restrict__ dst, int E,
        int* __restrict__ cursor, unsigned* __restrict__ pairs) {
    __shared__ __align__(16) char smem[GEMM_LDS_BYTES];
    int t = threadIdx.x;

    if ((int)blockIdx.x >= gb) {
        int* hist  = (int*)smem;          // 512 ints
        int* start = hist + 512;          // 512 ints
        hist[t] = 0;
        __syncthreads();
        int e00 = ((int)blockIdx.x - gb) * EBLK;

        // pass 1: per-bucket histogram (512 threads, 4 chunks of 2048 edges)
#pragma unroll
        for (int ch = 0; ch < EBLK / 2048; ch++) {
            int e = e00 + ch * 2048 + t * 4;
            if (e + 3 < E) {
                int4 dv = *(const int4*)&dst[e];
                atomicAdd(&hist[dv.x >> NBSHIFT], 1);
                atomicAdd(&hist[dv.y >> NBSHIFT], 1);
                atomicAdd(&hist[dv.z >> NBSHIFT], 1);
                atomicAdd(&hist[dv.w >> NBSHIFT], 1);
            } else {
                for (int i = 0; i < 4; i++)
                    if (e + i < E) atomicAdd(&hist[dst[e + i] >> NBSHIFT], 1);
            }
        }
        __syncthreads();
        if (hist[t] > 0) start[t] = atomicAdd(&cursor[t], hist[t]);
        __syncthreads();
        hist[t] = 0;   // reuse as rank counters
        __syncthreads();
        // pass 2: placement (re-read edges; L2-warm)
#pragma unroll
        for (int ch = 0; ch < EBLK / 2048; ch++) {
            int e = e00 + ch * 2048 + t * 4;
            if (e + 3 < E) {
                int4 dv = *(const int4*)&dst[e];
                int4 sv = *(const int4*)&src[e];
                int b0 = dv.x >> NBSHIFT; int r0 = atomicAdd(&hist[b0], 1);
                pairs[b0 * CAP + start[b0] + r0] = ((unsigned)(dv.x & (BSZ - 1)) << 17) | (unsigned)sv.x;
                int b1 = dv.y >> NBSHIFT; int r1 = atomicAdd(&hist[b1], 1);
                pairs[b1 * CAP + start[b1] + r1] = ((unsigned)(dv.y & (BSZ - 1)) << 17) | (unsigned)sv.y;
                int b2 = dv.z >> NBSHIFT; int r2 = atomicAdd(&hist[b2], 1);
                pairs[b2 * CAP + start[b2] + r2] = ((unsigned)(dv.z & (BSZ - 1)) << 17) | (unsigned)sv.z;
                int b3 = dv.w >> NBSHIFT; int r3 = atomicAdd(&hist[b3], 1);
                pairs[b3 * CAP + start[b3] + r3] = ((unsigned)(dv.w & (BSZ - 1)) << 17) | (unsigned)sv.w;
            } else {
                for (int i = 0; i < 4; i++) {
                    if (e + i < E) {
                        int d = dst[e + i], s = src[e + i];
                        int b = d >> NBSHIFT;
                        int r = atomicAdd(&hist[b], 1);
                        pairs[b * CAP + start[b] + r] = ((unsigned)(d & (BSZ - 1)) << 17) | (unsigned)s;
                    }
                }
            }
        }
        return;
    }

    gemm_body<false>(X, W1s, W1d, a1d, a1s, Y, a_s, a_d, N, blockIdx.x, smem);
}

// ---------------- standalone layer-2 GEMM (fp16 input h) ----------------
__global__ __launch_bounds__(512, 8) void k_gemm2(
        const __half* __restrict__ X, const float* __restrict__ W2s,
        const float* __restrict__ W2d, const float* __restrict__ a2d,
        const float* __restrict__ a2s,
        __half* __restrict__ Y, float* __restrict__ a_s, float* __restrict__ a_d, int N) {
    __shared__ __align__(16) char smem[GEMM_LDS_BYTES];
    gemm_body<true>(X, W2s, W2d, a2d, a2s, Y, a_s, a_d, N, blockIdx.x, smem);
}

// ---------------- kB: per-bucket CSR finalize (round-6 version) ----------------
__global__ __launch_bounds__(256) void kB_csr(const unsigned* __restrict__ pairs,
                                              const int* __restrict__ cursor,
                                              int* __restrict__ row_start, int* __restrict__ row_end,
                                              int* __restrict__ csr_src, int N) {
    __shared__ int cnt[BSZ];
    __shared__ int cur[BSZ];
    __shared__ int sS[256];
    int b = blockIdx.x, t = threadIdx.x;
    int base = b * CAP;
    int ecnt = cursor[b];
    int nodeBase = b << NBSHIFT;
    cnt[t] = 0;
    __syncthreads();
    for (int j = t; j < ecnt; j += 256)
        atomicAdd(&cnt[pairs[base + j] >> 17], 1);
    __syncthreads();
    int c0 = cnt[t];
    sS[t] = c0; __syncthreads();
    for (int off = 1; off < 256; off <<= 1) {
        int x = (t >= off) ? sS[t - off] : 0;
        __syncthreads();
        sS[t] += x;
        __syncthreads();
    }
    int excl = sS[t] - c0;
    cur[t] = excl;
    int g = nodeBase + t;
    if (g < N) { row_start[g] = base + excl; row_end[g] = base + excl + c0; }
    __syncthreads();
    for (int j = t; j < ecnt; j += 256) {
        unsigned p = pairs[base + j];
        int r = atomicAdd(&cur[p >> 17], 1);
        csr_src[base + r] = (int)(p & 0x1FFFFu);
    }
}

// ---------------- per-dst-node softmax + aggregation: quad-per-node (round-6 best) ----------------
// Wave = 4 nodes (one per quad), block = 16 nodes. 59us/pass, ~6.8 TB/s
// delivered gather bytes — rate-limited floor per rounds 6/9/10 A/B evidence.

__device__ __forceinline__ void fma_mix2(float& a0, float& a1, unsigned h2, float w) {
    asm("v_fma_mix_f32 %0, %1, %2, %0 op_sel_hi:[1,0,0]" : "+v"(a0) : "v"(h2), "v"(w));
    asm("v_fma_mix_f32 %0, %1, %2, %0 op_sel:[1,0,0] op_sel_hi:[1,0,0]" : "+v"(a1) : "v"(h2), "v"(w));
}

#define ACC_MIX(u, wj)  do {                                    \
    const unsigned* _w32 = (const unsigned*)&(u);               \
    fma_mix2(acc[0], acc[1], _w32[0], (wj));                    \
    fma_mix2(acc[2], acc[3], _w32[1], (wj));                    \
    fma_mix2(acc[4], acc[5], _w32[2], (wj));                    \
    fma_mix2(acc[6], acc[7], _w32[3], (wj));                    \
} while (0)

template <bool HEAD>
__global__ __launch_bounds__(256, 6) void k_agg(const int* __restrict__ csr_src, const int* __restrict__ rs_,
                                                const int* __restrict__ re_,
                                                const float* __restrict__ a_s, const float* __restrict__ a_d,
                                                const __half* __restrict__ xs, const float* __restrict__ bias,
                                                const float* __restrict__ Wl, const float* __restrict__ bl,
                                                void* __restrict__ outv, int N) {
    __shared__ int2 sP[4][4][16];
    int t = threadIdx.x; int wv = t >> 6, l = t & 63;
    int q = l >> 4, es = l & 15;
    int n = blockIdx.x * 16 + wv * 4 + q;
    bool nok = n < N;
    int rs0 = 0, deg = 0;
    if (nok) { rs0 = rs_[n]; deg = re_[n] - rs0; }
    float adn = nok ? a_d[n] : 0.f;
    const int* cs = csr_src + rs0;
    int c = es * 8;

    int R = (deg + 15) >> 4;            // rounds for this node
    R = max(R, __shfl_xor(R, 16));      // wave-uniform max
    R = max(R, __shfl_xor(R, 32));

    float acc[8];
#pragma unroll
    for (int k = 0; k < 8; k++) acc[k] = 0.f;
    float dnl = 0.f;
    int2 (*sq)[16] = sP[wv];            // wave-private

    for (int r = 0; r < R; ++r) {
        // ---- phase 1: parallel weight compute for 4 nodes x 16 edges ----
        int i = r * 16 + es;
        int idx = 0; float w = 0.f;
        if (i < deg) {
            idx = cs[i];
            float tv = a_s[idx] + adn;
            tv = tv > 0.f ? tv : 0.2f * tv;
            w = __expf(tv);
        }
        dnl += w;
        sq[q][es] = make_int2(idx, __float_as_int(w));  // same-wave LDS: lockstep ordering

        // ---- phase 2: quad q gathers its node's rows, 4-deep chains ----
        int rem = deg - r * 16;
        int mcq = rem >= 16 ? 16 : (rem > 0 ? ((rem + 3) & ~3) : 0);
        const int2* spq = sq[q];
        for (int e = 0; e < mcq; e += 4) {
            int4 pA = *(const int4*)&spq[e];        // edges e, e+1
            int4 pB = *(const int4*)&spq[e + 2];    // edges e+2, e+3
            uint4 u0 = *(const uint4*)&xs[(size_t)pA.x * 128 + c];
            uint4 u1 = *(const uint4*)&xs[(size_t)pA.z * 128 + c];
            uint4 u2 = *(const uint4*)&xs[(size_t)pB.x * 128 + c];
            uint4 u3 = *(const uint4*)&xs[(size_t)pB.z * 128 + c];
            ACC_MIX(u0, __int_as_float(pA.y));
            ACC_MIX(u1, __int_as_float(pA.w));
            ACC_MIX(u2, __int_as_float(pB.y));
            ACC_MIX(u3, __int_as_float(pB.w));
        }
    }

    // denominator: sum w over the 16 edge-slot lanes of this quad
    dnl += __shfl_xor(dnl, 1);
    dnl += __shfl_xor(dnl, 2);
    dnl += __shfl_xor(dnl, 4);
    dnl += __shfl_xor(dnl, 8);
    float inv = 1.f / (dnl + 1e-16f);

    float hv[8];
    float4 b0 = *(const float4*)&bias[c];
    float4 b1 = *(const float4*)&bias[c + 4];
    float bb[8] = {b0.x, b0.y, b0.z, b0.w, b1.x, b1.y, b1.z, b1.w};
#pragma unroll
    for (int k = 0; k < 8; k++) {
        float v = acc[k] * inv + bb[k];
        hv[k] = v > 0.f ? v : 0.f;
    }

    if (HEAD) {
        float p0 = 0.f, p1 = 0.f;
#pragma unroll
        for (int k = 0; k < 8; k++) {
            p0 += hv[k] * Wl[2 * (c + k)];
            p1 += hv[k] * Wl[2 * (c + k) + 1];
        }
        p0 += __shfl_xor(p0, 1); p0 += __shfl_xor(p0, 2);
        p0 += __shfl_xor(p0, 4); p0 += __shfl_xor(p0, 8);
        p1 += __shfl_xor(p1, 1); p1 += __shfl_xor(p1, 2);
        p1 += __shfl_xor(p1, 4); p1 += __shfl_xor(p1, 8);
        if (es == 0 && nok) {
            float* out = (float*)outv;
            out[2 * n]     = p0 + bl[0];
            out[2 * n + 1] = p1 + bl[1];
        }
    } else {
        // lane exclusively owns 8 channels: direct 16B fp16 store, 256B/quad
        if (nok) {
            __half* hout = (__half*)outv;
            __half hb[8];
#pragma unroll
            for (int k = 0; k < 8; k++) hb[k] = __float2half(hv[k]);
            *(uint4*)&hout[(size_t)n * 128 + c] = *(uint4*)hb;
        }
    }
}

// ---------------- launch ----------------

extern "C" void kernel_launch(void* const* d_in, const int* in_sizes, int n_in,
                              void* d_out, int out_size, void* d_ws, size_t ws_size,
                              hipStream_t stream) {
    const float* x   = (const float*)d_in[0];
    const int*   ei  = (const int*)d_in[1];
    const float* W1s = (const float*)d_in[2];
    const float* W1d = (const float*)d_in[3];
    const float* a1s = (const float*)d_in[4];
    const float* a1d = (const float*)d_in[5];
    const float* b1  = (const float*)d_in[6];
    const float* W2s = (const float*)d_in[7];
    const float* W2d = (const float*)d_in[8];
    const float* a2s = (const float*)d_in[9];
    const float* a2d = (const float*)d_in[10];
    const float* b2  = (const float*)d_in[11];
    const float* Wl  = (const float*)d_in[12];
    const float* bl  = (const float*)d_in[13];
    float* out = (float*)d_out;

    int N = in_sizes[0] / 128;
    int E = in_sizes[1] / 2;
    const int* srcA = ei;
    const int* dstA = ei + E;
    int NB = (N + BSZ - 1) >> NBSHIFT;

    // workspace layout
    __half* xs = (__half*)d_ws;                     // N*128 fp16  (25.6 MB)
    __half* h  = xs + (size_t)N * 128;              // N*128 fp16  (pairs aliases this)
    float* as_ = (float*)(h + (size_t)N * 128);     // N
    float* ad_ = as_ + N;                           // N
    int* row_start = (int*)(ad_ + N);               // N
    int* row_end   = row_start + N;                 // N
    int* csr_src   = row_end + N;                   // NB*CAP (8 MB)
    int* cursor    = csr_src + (size_t)NB * CAP;    // NB (zeroed via memset)
    unsigned* pairs = (unsigned*)h;                 // NB*CAP dwords (8 MB) <= h (25.6 MB);
                                                    // pairs written k_fuse1, read kB_csr;
                                                    // h first written k_agg<false> — no overlap

    int gb = (N + 127) / 128;                       // 128-row GEMM blocks (512 thr)
    int EB = (E + EBLK - 1) / EBLK;
    int ab = (N + 15) / 16;

    // 1) zero bucket cursors (1.5 KB DMA)
    hipMemsetAsync(cursor, 0, (size_t)NB * 4, stream);

    // 2) layer-1 GEMM fused with bucket pair placement
    k_fuse1<<<gb + EB, 512, 0, stream>>>(x, W1s, W1d, a1d, a1s, xs, as_, ad_, N, gb,
                                         srcA, dstA, E, cursor, pairs);

    // 3) per-bucket CSR finalize
    kB_csr<<<NB, 256, 0, stream>>>(pairs, cursor, row_start, row_end, csr_src, N);

    // 4) layer-1 aggregation (writes fp16 h)
    k_agg<false><<<ab, 256, 0, stream>>>(csr_src, row_start, row_end, as_, ad_, xs, b1, nullptr, nullptr, h, N);

    // 5) layer-2 GEMM (fp16 input)
    k_gemm2<<<gb, 512, 0, stream>>>(h, W2s, W2d, a2d, a2s, xs, as_, ad_, N);

    // 6) layer-2 aggregation + head
    k_agg<true><<<ab, 256, 0, stream>>>(csr_src, row_start, row_end, as_, ad_, xs, b2, Wl, bl, out, N);
}

// Round 13
// 298.309 us; speedup vs baseline: 1.2586x; 1.2586x over previous
//
#include <hip/hip_runtime.h>
#include <hip/hip_fp16.h>

#define NBSHIFT 8
#define BSZ     256     // nodes per bucket
#define CAP     5120    // fixed bucket capacity (mean 4092, sigma 64 -> +16 sigma)
#define EBLK    8192    // edges per binning block

typedef _Float16 f16x8 __attribute__((ext_vector_type(8)));
typedef float    f32x4 __attribute__((ext_vector_type(4)));

#define GEMM_LDS_BYTES (128 * 136 * 2 + 512)

// ---------------- self-contained MFMA GEMM body: 512 threads, 128 rows ----------------
// Round-12 lesson: __launch_bounds__(512,8) capped VGPR at 32 -> acc[8] (32 VGPR)
// spilled to scratch (+116MB WRITE). (512,4) gives 128 VGPR/wave, 16 waves/CU.
// Staging (svd + sWh) serves 128 rows (2x amortization vs round-6's 64).
template <bool XHALF>
__device__ __forceinline__ void gemm_body(
        const void* __restrict__ Xv, const float* __restrict__ Ws,
        const float* __restrict__ Wd, const float* __restrict__ attd,
        const float* __restrict__ att,
        __half* __restrict__ Y, float* __restrict__ a_s, float* __restrict__ a_d,
        int N, int blk, char* smem) {
    _Float16 (*sWh)[136] = (_Float16(*)[136])smem;
    float* svd = (float*)(smem + 128 * 136 * 2);
    int t = threadIdx.x;

    // vd[k] = dot(Wd row k, attd)
    if (t < 128) {
        const float4* wr = (const float4*)&Wd[t * 128];
        const float4* ar = (const float4*)attd;
        float s = 0.f;
#pragma unroll 8
        for (int j = 0; j < 32; j++) {
            float4 w = wr[j], a = ar[j];
            s += w.x * a.x + w.y * a.y + w.z * a.z + w.w * a.w;
        }
        svd[t] = s;
    }
    // sWh[n][k] = (fp16) Ws[k*128+n]; 512 threads -> 8 iters
#pragma unroll
    for (int i = 0; i < 8; i++) {
        int gid = t + i * 512;       // 0..4095
        int n = gid & 127, kq = gid >> 7;
        _Float16 p[4];
        p[0] = (_Float16)Ws[(kq * 4 + 0) * 128 + n];
        p[1] = (_Float16)Ws[(kq * 4 + 1) * 128 + n];
        p[2] = (_Float16)Ws[(kq * 4 + 2) * 128 + n];
        p[3] = (_Float16)Ws[(kq * 4 + 3) * 128 + n];
        *(uint2*)&sWh[n][kq * 4] = *(uint2*)p;
    }
    __syncthreads();

    int l = t & 63, wv = t >> 6;          // wv: 0..7
    int quad = l >> 4, lm = l & 15;
    int rbase = blk * 128 + wv * 16;
    int arow = rbase + lm;
    bool rok = arow < N;

    f32x4 acc[8];
#pragma unroll
    for (int c = 0; c < 8; c++) acc[c] = (f32x4){0.f, 0.f, 0.f, 0.f};
    float adp = 0.f;

#pragma unroll
    for (int kc = 0; kc < 4; kc++) {
        int k0 = kc * 32 + quad * 8;
        float xf[8];
        f16x8 af;
        if constexpr (XHALF) {
            const __half* xrow = (const __half*)Xv + (size_t)arow * 128;
            if (rok) {
                af = *(const f16x8*)&xrow[k0];
            } else {
#pragma unroll
                for (int j = 0; j < 8; j++) af[j] = (_Float16)0.f;
            }
#pragma unroll
            for (int j = 0; j < 8; j++) xf[j] = (float)af[j];
        } else {
            const float* xrow = (const float*)Xv + (size_t)arow * 128;
            if (rok) {
                *(float4*)&xf[0] = *(const float4*)&xrow[k0];
                *(float4*)&xf[4] = *(const float4*)&xrow[k0 + 4];
            } else {
#pragma unroll
                for (int j = 0; j < 8; j++) xf[j] = 0.f;
            }
#pragma unroll
            for (int j = 0; j < 8; j++) af[j] = (_Float16)xf[j];
        }
        float4 v0 = *(const float4*)&svd[k0];       // broadcast within quad
        float4 v1 = *(const float4*)&svd[k0 + 4];
        adp += xf[0] * v0.x + xf[1] * v0.y + xf[2] * v0.z + xf[3] * v0.w
             + xf[4] * v1.x + xf[5] * v1.y + xf[6] * v1.z + xf[7] * v1.w;
#pragma unroll
        for (int c = 0; c < 8; c++) {
            f16x8 bf = *(const f16x8*)&sWh[c * 16 + lm][k0];   // col n = c*16+lm
            acc[c] = __builtin_amdgcn_mfma_f32_16x16x32_f16(af, bf, acc[c], 0, 0, 0);
        }
    }

    adp += __shfl_xor(adp, 16);
    adp += __shfl_xor(adp, 32);
    if (quad == 0 && rok) a_d[arow] = adp;

    float attc[8];
#pragma unroll
    for (int c = 0; c < 8; c++) attc[c] = att[c * 16 + lm];
#pragma unroll
    for (int r = 0; r < 4; r++) {
        int grow = rbase + quad * 4 + r;
        bool gok = grow < N;
        float p = 0.f;
#pragma unroll
        for (int c = 0; c < 8; c++) {
            if (gok) Y[(size_t)grow * 128 + c * 16 + lm] = __float2half(acc[c][r]);
            p += acc[c][r] * attc[c];
        }
        p += __shfl_xor(p, 1); p += __shfl_xor(p, 2); p += __shfl_xor(p, 4); p += __shfl_xor(p, 8);
        if (lm == 0 && gok) a_s[grow] = p;
    }
}

// ---------------- FUSED: layer-1 GEMM (blocks < gb) + bucket pair placement ----------------
__global__ __launch_bounds__(512, 4) void k_fuse1(
        const float* __restrict__ X, const float* __restrict__ W1s,
        const float* __restrict__ W1d, const float* __restrict__ a1d,
        const float* __restrict__ a1s,
        __half* __restrict__ Y, float* __restrict__ a_s, float* __restrict__ a_d, int N, int gb,
        const int* __restrict__ src, const int* __restrict__ dst, int E,
        int* __restrict__ cursor, unsigned* __restrict__ pairs) {
    __shared__ __align__(16) char smem[GEMM_LDS_BYTES];
    int t = threadIdx.x;

    if ((int)blockIdx.x >= gb) {
        int* hist  = (int*)smem;          // 512 ints
        int* start = hist + 512;          // 512 ints
        hist[t] = 0;
        __syncthreads();
        int e00 = ((int)blockIdx.x - gb) * EBLK;

        // pass 1: per-bucket histogram (512 threads, 4 chunks of 2048 edges)
#pragma unroll
        for (int ch = 0; ch < EBLK / 2048; ch++) {
            int e = e00 + ch * 2048 + t * 4;
            if (e + 3 < E) {
                int4 dv = *(const int4*)&dst[e];
                atomicAdd(&hist[dv.x >> NBSHIFT], 1);
                atomicAdd(&hist[dv.y >> NBSHIFT], 1);
                atomicAdd(&hist[dv.z >> NBSHIFT], 1);
                atomicAdd(&hist[dv.w >> NBSHIFT], 1);
            } else {
                for (int i = 0; i < 4; i++)
                    if (e + i < E) atomicAdd(&hist[dst[e + i] >> NBSHIFT], 1);
            }
        }
        __syncthreads();
        if (hist[t] > 0) start[t] = atomicAdd(&cursor[t], hist[t]);
        __syncthreads();
        hist[t] = 0;   // reuse as rank counters
        __syncthreads();
        // pass 2: placement (re-read edges; L2-warm)
#pragma unroll
        for (int ch = 0; ch < EBLK / 2048; ch++) {
            int e = e00 + ch * 2048 + t * 4;
            if (e + 3 < E) {
                int4 dv = *(const int4*)&dst[e];
                int4 sv = *(const int4*)&src[e];
                int b0 = dv.x >> NBSHIFT; int r0 = atomicAdd(&hist[b0], 1);
                pairs[b0 * CAP + start[b0] + r0] = ((unsigned)(dv.x & (BSZ - 1)) << 17) | (unsigned)sv.x;
                int b1 = dv.y >> NBSHIFT; int r1 = atomicAdd(&hist[b1], 1);
                pairs[b1 * CAP + start[b1] + r1] = ((unsigned)(dv.y & (BSZ - 1)) << 17) | (unsigned)sv.y;
                int b2 = dv.z >> NBSHIFT; int r2 = atomicAdd(&hist[b2], 1);
                pairs[b2 * CAP + start[b2] + r2] = ((unsigned)(dv.z & (BSZ - 1)) << 17) | (unsigned)sv.z;
                int b3 = dv.w >> NBSHIFT; int r3 = atomicAdd(&hist[b3], 1);
                pairs[b3 * CAP + start[b3] + r3] = ((unsigned)(dv.w & (BSZ - 1)) << 17) | (unsigned)sv.w;
            } else {
                for (int i = 0; i < 4; i++) {
                    if (e + i < E) {
                        int d = dst[e + i], s = src[e + i];
                        int b = d >> NBSHIFT;
                        int r = atomicAdd(&hist[b], 1);
                        pairs[b * CAP + start[b] + r] = ((unsigned)(d & (BSZ - 1)) << 17) | (unsigned)s;
                    }
                }
            }
        }
        return;
    }

    gemm_body<false>(X, W1s, W1d, a1d, a1s, Y, a_s, a_d, N, blockIdx.x, smem);
}

// ---------------- standalone layer-2 GEMM (fp16 input h) ----------------
__global__ __launch_bounds__(512, 4) void k_gemm2(
        const __half* __restrict__ X, const float* __restrict__ W2s,
        const float* __restrict__ W2d, const float* __restrict__ a2d,
        const float* __restrict__ a2s,
        __half* __restrict__ Y, float* __restrict__ a_s, float* __restrict__ a_d, int N) {
    __shared__ __align__(16) char smem[GEMM_LDS_BYTES];
    gemm_body<true>(X, W2s, W2d, a2d, a2s, Y, a_s, a_d, N, blockIdx.x, smem);
}

// ---------------- kB: per-bucket CSR finalize (round-6 version) ----------------
__global__ __launch_bounds__(256) void kB_csr(const unsigned* __restrict__ pairs,
                                              const int* __restrict__ cursor,
                                              int* __restrict__ row_start, int* __restrict__ row_end,
                                              int* __restrict__ csr_src, int N) {
    __shared__ int cnt[BSZ];
    __shared__ int cur[BSZ];
    __shared__ int sS[256];
    int b = blockIdx.x, t = threadIdx.x;
    int base = b * CAP;
    int ecnt = cursor[b];
    int nodeBase = b << NBSHIFT;
    cnt[t] = 0;
    __syncthreads();
    for (int j = t; j < ecnt; j += 256)
        atomicAdd(&cnt[pairs[base + j] >> 17], 1);
    __syncthreads();
    int c0 = cnt[t];
    sS[t] = c0; __syncthreads();
    for (int off = 1; off < 256; off <<= 1) {
        int x = (t >= off) ? sS[t - off] : 0;
        __syncthreads();
        sS[t] += x;
        __syncthreads();
    }
    int excl = sS[t] - c0;
    cur[t] = excl;
    int g = nodeBase + t;
    if (g < N) { row_start[g] = base + excl; row_end[g] = base + excl + c0; }
    __syncthreads();
    for (int j = t; j < ecnt; j += 256) {
        unsigned p = pairs[base + j];
        int r = atomicAdd(&cur[p >> 17], 1);
        csr_src[base + r] = (int)(p & 0x1FFFFu);
    }
}

// ---------------- per-dst-node softmax + aggregation: quad-per-node (round-6 best) ----------------
// Wave = 4 nodes (one per quad), block = 16 nodes. 59us/pass, ~6.8 TB/s
// delivered gather bytes — rate-limited floor per rounds 6/9/10 A/B evidence.

__device__ __forceinline__ void fma_mix2(float& a0, float& a1, unsigned h2, float w) {
    asm("v_fma_mix_f32 %0, %1, %2, %0 op_sel_hi:[1,0,0]" : "+v"(a0) : "v"(h2), "v"(w));
    asm("v_fma_mix_f32 %0, %1, %2, %0 op_sel:[1,0,0] op_sel_hi:[1,0,0]" : "+v"(a1) : "v"(h2), "v"(w));
}

#define ACC_MIX(u, wj)  do {                                    \
    const unsigned* _w32 = (const unsigned*)&(u);               \
    fma_mix2(acc[0], acc[1], _w32[0], (wj));                    \
    fma_mix2(acc[2], acc[3], _w32[1], (wj));                    \
    fma_mix2(acc[4], acc[5], _w32[2], (wj));                    \
    fma_mix2(acc[6], acc[7], _w32[3], (wj));                    \
} while (0)

template <bool HEAD>
__global__ __launch_bounds__(256, 6) void k_agg(const int* __restrict__ csr_src, const int* __restrict__ rs_,
                                                const int* __restrict__ re_,
                                                const float* __restrict__ a_s, const float* __restrict__ a_d,
                                                const __half* __restrict__ xs, const float* __restrict__ bias,
                                                const float* __restrict__ Wl, const float* __restrict__ bl,
                                                void* __restrict__ outv, int N) {
    __shared__ int2 sP[4][4][16];
    int t = threadIdx.x; int wv = t >> 6, l = t & 63;
    int q = l >> 4, es = l & 15;
    int n = blockIdx.x * 16 + wv * 4 + q;
    bool nok = n < N;
    int rs0 = 0, deg = 0;
    if (nok) { rs0 = rs_[n]; deg = re_[n] - rs0; }
    float adn = nok ? a_d[n] : 0.f;
    const int* cs = csr_src + rs0;
    int c = es * 8;

    int R = (deg + 15) >> 4;            // rounds for this node
    R = max(R, __shfl_xor(R, 16));      // wave-uniform max
    R = max(R, __shfl_xor(R, 32));

    float acc[8];
#pragma unroll
    for (int k = 0; k < 8; k++) acc[k] = 0.f;
    float dnl = 0.f;
    int2 (*sq)[16] = sP[wv];            // wave-private

    for (int r = 0; r < R; ++r) {
        // ---- phase 1: parallel weight compute for 4 nodes x 16 edges ----
        int i = r * 16 + es;
        int idx = 0; float w = 0.f;
        if (i < deg) {
            idx = cs[i];
            float tv = a_s[idx] + adn;
            tv = tv > 0.f ? tv : 0.2f * tv;
            w = __expf(tv);
        }
        dnl += w;
        sq[q][es] = make_int2(idx, __float_as_int(w));  // same-wave LDS: lockstep ordering

        // ---- phase 2: quad q gathers its node's rows, 4-deep chains ----
        int rem = deg - r * 16;
        int mcq = rem >= 16 ? 16 : (rem > 0 ? ((rem + 3) & ~3) : 0);
        const int2* spq = sq[q];
        for (int e = 0; e < mcq; e += 4) {
            int4 pA = *(const int4*)&spq[e];        // edges e, e+1
            int4 pB = *(const int4*)&spq[e + 2];    // edges e+2, e+3
            uint4 u0 = *(const uint4*)&xs[(size_t)pA.x * 128 + c];
            uint4 u1 = *(const uint4*)&xs[(size_t)pA.z * 128 + c];
            uint4 u2 = *(const uint4*)&xs[(size_t)pB.x * 128 + c];
            uint4 u3 = *(const uint4*)&xs[(size_t)pB.z * 128 + c];
            ACC_MIX(u0, __int_as_float(pA.y));
            ACC_MIX(u1, __int_as_float(pA.w));
            ACC_MIX(u2, __int_as_float(pB.y));
            ACC_MIX(u3, __int_as_float(pB.w));
        }
    }

    // denominator: sum w over the 16 edge-slot lanes of this quad
    dnl += __shfl_xor(dnl, 1);
    dnl += __shfl_xor(dnl, 2);
    dnl += __shfl_xor(dnl, 4);
    dnl += __shfl_xor(dnl, 8);
    float inv = 1.f / (dnl + 1e-16f);

    float hv[8];
    float4 b0 = *(const float4*)&bias[c];
    float4 b1 = *(const float4*)&bias[c + 4];
    float bb[8] = {b0.x, b0.y, b0.z, b0.w, b1.x, b1.y, b1.z, b1.w};
#pragma unroll
    for (int k = 0; k < 8; k++) {
        float v = acc[k] * inv + bb[k];
        hv[k] = v > 0.f ? v : 0.f;
    }

    if (HEAD) {
        float p0 = 0.f, p1 = 0.f;
#pragma unroll
        for (int k = 0; k < 8; k++) {
            p0 += hv[k] * Wl[2 * (c + k)];
            p1 += hv[k] * Wl[2 * (c + k) + 1];
        }
        p0 += __shfl_xor(p0, 1); p0 += __shfl_xor(p0, 2);
        p0 += __shfl_xor(p0, 4); p0 += __shfl_xor(p0, 8);
        p1 += __shfl_xor(p1, 1); p1 += __shfl_xor(p1, 2);
        p1 += __shfl_xor(p1, 4); p1 += __shfl_xor(p1, 8);
        if (es == 0 && nok) {
            float* out = (float*)outv;
            out[2 * n]     = p0 + bl[0];
            out[2 * n + 1] = p1 + bl[1];
        }
    } else {
        // lane exclusively owns 8 channels: direct 16B fp16 store, 256B/quad
        if (nok) {
            __half* hout = (__half*)outv;
            __half hb[8];
#pragma unroll
            for (int k = 0; k < 8; k++) hb[k] = __float2half(hv[k]);
            *(uint4*)&hout[(size_t)n * 128 + c] = *(uint4*)hb;
        }
    }
}

// ---------------- launch ----------------

extern "C" void kernel_launch(void* const* d_in, const int* in_sizes, int n_in,
                              void* d_out, int out_size, void* d_ws, size_t ws_size,
                              hipStream_t stream) {
    const float* x   = (const float*)d_in[0];
    const int*   ei  = (const int*)d_in[1];
    const float* W1s = (const float*)d_in[2];
    const float* W1d = (const float*)d_in[3];
    const float* a1s = (const float*)d_in[4];
    const float* a1d = (const float*)d_in[5];
    const float* b1  = (const float*)d_in[6];
    const float* W2s = (const float*)d_in[7];
    const float* W2d = (const float*)d_in[8];
    const float* a2s = (const float*)d_in[9];
    const float* a2d = (const float*)d_in[10];
    const float* b2  = (const float*)d_in[11];
    const float* Wl  = (const float*)d_in[12];
    const float* bl  = (const float*)d_in[13];
    float* out = (float*)d_out;

    int N = in_sizes[0] / 128;
    int E = in_sizes[1] / 2;
    const int* srcA = ei;
    const int* dstA = ei + E;
    int NB = (N + BSZ - 1) >> NBSHIFT;

    // workspace layout
    __half* xs = (__half*)d_ws;                     // N*128 fp16  (25.6 MB)
    __half* h  = xs + (size_t)N * 128;              // N*128 fp16  (pairs aliases this)
    float* as_ = (float*)(h + (size_t)N * 128);     // N
    float* ad_ = as_ + N;                           // N
    int* row_start = (int*)(ad_ + N);               // N
    int* row_end   = row_start + N;                 // N
    int* csr_src   = row_end + N;                   // NB*CAP (8 MB)
    int* cursor    = csr_src + (size_t)NB * CAP;    // NB (zeroed via memset)
    unsigned* pairs = (unsigned*)h;                 // NB*CAP dwords (8 MB) <= h (25.6 MB);
                                                    // pairs written k_fuse1, read kB_csr;
                                                    // h first written k_agg<false> — no overlap

    int gb = (N + 127) / 128;                       // 128-row GEMM blocks (512 thr)
    int EB = (E + EBLK - 1) / EBLK;
    int ab = (N + 15) / 16;

    // 1) zero bucket cursors (1.5 KB DMA)
    hipMemsetAsync(cursor, 0, (size_t)NB * 4, stream);

    // 2) layer-1 GEMM fused with bucket pair placement
    k_fuse1<<<gb + EB, 512, 0, stream>>>(x, W1s, W1d, a1d, a1s, xs, as_, ad_, N, gb,
                                         srcA, dstA, E, cursor, pairs);

    // 3) per-bucket CSR finalize
    kB_csr<<<NB, 256, 0, stream>>>(pairs, cursor, row_start, row_end, csr_src, N);

    // 4) layer-1 aggregation (writes fp16 h)
    k_agg<false><<<ab, 256, 0, stream>>>(csr_src, row_start, row_end, as_, ad_, xs, b1, nullptr, nullptr, h, N);

    // 5) layer-2 GEMM (fp16 input)
    k_gemm2<<<gb, 512, 0, stream>>>(h, W2s, W2d, a2d, a2s, xs, as_, ad_, N);

    // 6) layer-2 aggregation + head
    k_agg<true><<<ab, 256, 0, stream>>>(csr_src, row_start, row_end, as_, ad_, xs, b2, Wl, bl, out, N);
}